// Round 1
// baseline (579.537 us; speedup 1.0000x reference)
//
#include <hip/hip_runtime.h>

// ILCBaseNode: T=32 steps of IF-neuron + grouped-conv feedback.
// One wave (64 lanes) per (batch, group) chain; lane o = output neuron o.
// 32768 chains = 8192 blocks x 4 waves.

#define T_STEPS 32
#define BATCH 512
#define OUTD 4096           // 64 groups * 64 neurons
#define STEP_STRIDE ((size_t)BATCH * OUTD)

__global__ __launch_bounds__(256, 4)
void ilc_snn_kernel(const float* __restrict__ x_seq,
                    const float* __restrict__ conn_w,
                    const float* __restrict__ conn_b,
                    float* __restrict__ out)
{
    const int lane  = threadIdx.x & 63;
    const int wid   = threadIdx.x >> 6;
    const int chain = blockIdx.x * 4 + wid;   // 0..32767
    const int b     = chain >> 6;             // 0..511
    const int a     = chain & 63;             // 0..63

    // Lane o holds weight row w[a][o][0..63] in registers (64 VGPRs).
    float w[64];
    const float* wrow = conn_w + ((size_t)(a * 64 + lane)) * 64;
#pragma unroll
    for (int k = 0; k < 16; ++k) {
        const float4 q = *(const float4*)(wrow + 4 * k);
        w[4 * k + 0] = q.x;
        w[4 * k + 1] = q.y;
        w[4 * k + 2] = q.z;
        w[4 * k + 3] = q.w;
    }
    const float bias = conn_b[a * 64 + lane];

    const size_t base = (size_t)b * OUTD + (size_t)(a * 64 + lane);
    const float* xp = x_seq + base;
    float* op = out + base;

    float v = 0.0f, fb = 0.0f;
    float xt = xp[0];   // prefetch step 0

    for (int t = 0; t < T_STEPS; ++t) {
        // Prefetch next step's input before the long fmac chain.
        float xnext = 0.0f;
        if (t + 1 < T_STEPS) xnext = xp[(size_t)(t + 1) * STEP_STRIDE];

        // Charge
        const float x = xt + fb;   // x_t + feedback (matches ref op order)
        v = v + x;
        // Fire (heaviside on v - 1.0)
        const bool  sp = (v - 1.0f) >= 0.0f;
        const float sf = sp ? 1.0f : 0.0f;
        // Hard reset
        v = sp ? 0.0f : v;
        // Emit spike
        op[(size_t)t * STEP_STRIDE] = sf;

        // Feedback matvec: fb[o] = sum_{d=0..63} s[d] * w[o][d] + bias[o]
        // Strict left-to-right order, single accumulator (matches sequential
        // fp32 summation; fmaf exact since s[d] in {0,1}).
        float acc = 0.0f;
        int sfi = __builtin_bit_cast(int, sf);
#pragma unroll
        for (int d = 0; d < 64; ++d) {
            const int   sdi = __builtin_amdgcn_readlane(sfi, d);
            const float sd  = __builtin_bit_cast(float, sdi);
            acc = fmaf(sd, w[d], acc);
        }
        fb = acc + bias;

        xt = xnext;
    }
}

extern "C" void kernel_launch(void* const* d_in, const int* in_sizes, int n_in,
                              void* d_out, int out_size, void* d_ws, size_t ws_size,
                              hipStream_t stream) {
    const float* x_seq  = (const float*)d_in[0];
    const float* conn_w = (const float*)d_in[1];
    const float* conn_b = (const float*)d_in[2];
    float* out = (float*)d_out;

    dim3 grid(8192);   // 32768 chains / 4 waves per block
    dim3 block(256);
    hipLaunchKernelGGL(ilc_snn_kernel, grid, block, 0, stream,
                       x_seq, conn_w, conn_b, out);
}